// Round 4
// baseline (230.263 us; speedup 1.0000x reference)
//
#include <hip/hip_runtime.h>

#define NN 50000
#define EE 800000

#define BKT 196      // buckets = dst>>8 (256 nodes each)
#define GB  334      // scatter blocks
#define EPB 2396     // edges per block (334*2396 = 800264 >= E)
#define CAPB 6144    // fixed bucket capacity (mean 4096, +32 sigma)
#define CAP 5120     // LDS staging capacity in bucket_sort

typedef unsigned short u16;
typedef unsigned int u32;
typedef __attribute__((ext_vector_type(8))) short short8;   // 8 bf16 (4 VGPRs)
typedef __attribute__((ext_vector_type(4))) float f32x4;
typedef __attribute__((ext_vector_type(4))) unsigned short ushort4v;

__device__ __forceinline__ float b2f(u16 u) {
    return __uint_as_float(((unsigned)u) << 16);
}
__device__ __forceinline__ u16 f2b(float f) {
    unsigned u = __float_as_uint(f);
    return (u16)((u + 0x7FFF + ((u >> 16) & 1)) >> 16);   // RNE
}

// ---------------------------------------------------------------------------
// K1: blocks 0..23 pack W0/W1/W2(padded) into MFMA B-fragment order;
//     block 24 inits the 196 global bucket cursors to b*CAPB.
// ---------------------------------------------------------------------------
__global__ __launch_bounds__(256) void prep_init(
    const float* __restrict__ W0, const float* __restrict__ W1,
    const float* __restrict__ W2, u16* __restrict__ Wf,
    int* __restrict__ gCur)
{
    const int g = blockIdx.x, t = threadIdx.x;
    if (g == 24) {
        if (t < BKT) gCur[t] = t * CAPB;
        return;
    }
    int u = g * 4 + (t >> 6);               // 0..95
    int set = u >> 5, nt2 = (u >> 2) & 7, kt = u & 3;
    int lane = t & 63;
    const float* W = (set == 0) ? W0 : (set == 1) ? W1 : W2;
    int ld = (set == 2) ? 40 : 128;
    int ncols = (set == 2) ? 40 : 128;
    int n = nt2 * 16 + (lane & 15);
    int kb = kt * 32 + (lane >> 4) * 8;
    u16* dw = Wf + set * 16384 + (size_t)((nt2 * 4 + kt) * 64 + lane) * 8;
#pragma unroll
    for (int j = 0; j < 8; j++) {
        float v = (n < ncols) ? W[(kb + j) * ld + n] : 0.f;
        dw[j] = f2b(v);
    }
}

// ---------------------------------------------------------------------------
// K2: blocks [0,GB): 2-pass scatter with atomic batch reservation.
//     blocks [GB,..): layer-0 GEMM  t = bf16(x) @ W0.
// ---------------------------------------------------------------------------
__global__ __launch_bounds__(256) void scatter_gemm0(
    const int* __restrict__ src, const int* __restrict__ dst,
    int* __restrict__ gCur, u32* __restrict__ pairs,
    const float* __restrict__ A, const u16* __restrict__ Wf,
    u16* __restrict__ out, int N, int E)
{
    __shared__ int cnt[BKT];
    __shared__ int cur[BKT];
    const int t = threadIdx.x;
    if (blockIdx.x < GB) {
        const int g = blockIdx.x;
        for (int b = t; b < BKT; b += 256) cnt[b] = 0;
        __syncthreads();
        const int beg = g * EPB, end = min(E, beg + EPB);
        for (int e = beg + t; e < end; e += 256)
            atomicAdd(&cnt[dst[e] >> 8], 1);
        __syncthreads();
        for (int b = t; b < BKT; b += 256)
            cur[b] = atomicAdd(&gCur[b], cnt[b]);
        __syncthreads();
        for (int e = beg + t; e < end; e += 256) {
            int d = dst[e];
            int pos = atomicAdd(&cur[d >> 8], 1);
            pairs[pos] = ((u32)src[e] << 8) | (u32)(d & 255);
        }
        return;
    }
    // ---- gemm0 ----
    const int bx = blockIdx.x - GB;
    const int wave = t >> 6;
    const int lane = t & 63;
    const int m = lane & 15;
    const int q = lane >> 4;
    const int rowBase = bx * 64 + wave * 16;
    const int arow = rowBase + m;
    const bool rowOk = (arow < N);

    short8 af[4];
#pragma unroll
    for (int kt = 0; kt < 4; kt++) {
        if (rowOk) {
            float4 lo = *(const float4*)(A + (size_t)arow * 128 + kt * 32 + q * 8);
            float4 hi = *(const float4*)(A + (size_t)arow * 128 + kt * 32 + q * 8 + 4);
            short8 v;
            v[0] = (short)f2b(lo.x); v[1] = (short)f2b(lo.y);
            v[2] = (short)f2b(lo.z); v[3] = (short)f2b(lo.w);
            v[4] = (short)f2b(hi.x); v[5] = (short)f2b(hi.y);
            v[6] = (short)f2b(hi.z); v[7] = (short)f2b(hi.w);
            af[kt] = v;
        } else {
            af[kt] = (short8)0;
        }
    }

    f32x4 acc[8];
#pragma unroll
    for (int nt = 0; nt < 8; nt++) acc[nt] = (f32x4)0.f;

#pragma unroll
    for (int kt = 0; kt < 4; kt++) {
#pragma unroll
        for (int nt = 0; nt < 8; nt++) {
            short8 bf = *(const short8*)(Wf + (size_t)((nt * 4 + kt) * 64 + lane) * 8);
            acc[nt] = __builtin_amdgcn_mfma_f32_16x16x32_bf16(af[kt], bf, acc[nt], 0, 0, 0);
        }
    }

#pragma unroll
    for (int nt = 0; nt < 8; nt++) {
#pragma unroll
        for (int r = 0; r < 4; r++) {
            int orow = rowBase + q * 4 + r;
            if (orow < N) out[(size_t)orow * 128 + nt * 16 + m] = f2b(acc[nt][r]);
        }
    }
}

// ---------------------------------------------------------------------------
// K3: per-bucket node sort (round-0 256-key version).
// ---------------------------------------------------------------------------
__global__ __launch_bounds__(256) void bucket_sort(
    const u32* __restrict__ pairs, const int* __restrict__ gCur,
    int* __restrict__ off, int* __restrict__ csr, int N, int E)
{
    __shared__ int sdeg[256];
    __shared__ int sex[256];
    __shared__ int scur[256];
    __shared__ int stage[CAP];
    const int b = blockIdx.x, t = threadIdx.x;

    int c0 = (t < BKT) ? (gCur[t] - t * CAPB) : 0;
    sex[t] = c0;
    __syncthreads();
    for (int d = 1; d < 256; d <<= 1) {
        int u = (t >= d) ? sex[t - d] : 0;
        __syncthreads();
        sex[t] += u;
        __syncthreads();
    }
    __shared__ int sBase, sCnt;
    if (t == b) { sBase = sex[t] - c0; sCnt = c0; }
    __syncthreads();
    const int base = sBase;
    const int cnt = sCnt;
    const int pbase = b * CAPB;
    __syncthreads();

    sdeg[t] = 0;
    __syncthreads();
    for (int i = t; i < cnt; i += 256)
        atomicAdd(&sdeg[pairs[pbase + i] & 255], 1);
    __syncthreads();

    int v = sdeg[t];
    sex[t] = v;
    __syncthreads();
    for (int d = 1; d < 256; d <<= 1) {
        int u = (t >= d) ? sex[t - d] : 0;
        __syncthreads();
        sex[t] += u;
        __syncthreads();
    }
    const int excl = sex[t] - v;
    const int node = b * 256 + t;
    if (node < N) off[node] = base + excl;
    if (b == BKT - 1 && t == 0) off[N] = E;
    scur[t] = excl;
    __syncthreads();

    if (cnt <= CAP) {
        for (int i = t; i < cnt; i += 256) {
            u32 p = pairs[pbase + i];
            int pos = atomicAdd(&scur[p & 255], 1);
            stage[pos] = (int)(p >> 8);
        }
        __syncthreads();
        for (int i = t; i < cnt; i += 256) csr[base + i] = stage[i];
    } else {
        for (int i = t; i < cnt; i += 256) {
            u32 p = pairs[pbase + i];
            int pos = atomicAdd(&scur[p & 255], 1);
            csr[base + pos] = (int)(p >> 8);
        }
    }
}

// ---------------------------------------------------------------------------
// K4/K5: FUSED layer: out = ( relu(agg(val) + bias) ) @ W
// block = 64 dst nodes, 512 threads (8 waves).
// phase 1: gather-aggregate with a 2-DEEP SOFTWARE PIPELINE:
//   while batch A's rows are consumed, batch B's rows are in flight and
//   batch C's csr indices are loading. R1's plain unroll-8 was burst-and-
//   drain (in-flight collapses to 0 at each loop back-edge); the rotation
//   keeps ~8 VMEM outstanding continuously and overlaps each batch's VALU
//   with the next batch's ~300cy L2/L3 latency. (Latency-bound: R3 counters
//   showed 23% HBM / 25% VALU / 1.2% MFMA -- nothing saturated.)
// phase 2: MFMA from LDS; wave = (rowGroup 0..3) x (colHalf 0..1)
// OCOLS clamps stores to the true output width (stride-40 clobber bug, R11).
// Plain stores (NT u16 stores write-amplified 2.3x, R3: WRITE 29.7 MB).
// __launch_bounds__(512,6): cap VGPR at ~85 so 3 blocks/CU stay resident.
// NOTE: val and out MUST differ (cross-block gather; in-place is a race).
// ---------------------------------------------------------------------------
template<int NT, int OSTRIDE, int OCOLS>
__global__ __launch_bounds__(512, 6) void agg_gemm_t(
    const u16* __restrict__ val, const int* __restrict__ off,
    const int* __restrict__ csr, const float* __restrict__ bias,
    const u16* __restrict__ Wf, u16* __restrict__ out, int N)
{
    __shared__ u16 A[64][136];   // 17.4 KB
    const int tid = threadIdx.x;
    const int rowBase = blockIdx.x * 64;

    // ---- phase 1: aggregate, bias+relu, bf16 -> LDS
    {
        const int c = tid & 15;          // 16B chunk (8 bf16)
        const int nl = tid >> 4;         // 0..31
        const u16* vb = val + c * 8;     // hoisted column base
        float4 bA = *(const float4*)(bias + c * 8);
        float4 bB = *(const float4*)(bias + c * 8 + 4);
        float bb[8] = {bA.x, bA.y, bA.z, bA.w, bB.x, bB.y, bB.z, bB.w};
#define ROWL(s) (*(const short8*)(vb + (size_t)(s) * 128))
#pragma unroll
        for (int g = 0; g < 2; g++) {
            const int lrow = g * 32 + nl;
            const int node = rowBase + lrow;
            float a0[8] = {0, 0, 0, 0, 0, 0, 0, 0};
            float a1[8] = {0, 0, 0, 0, 0, 0, 0, 0};
            if (node < N) {
                const int beg = off[node], end = off[node + 1];
                int i = beg;
                if (end - i >= 8) {
                    // prologue: rows of batch A in flight, csr of batch B loaded
                    int s0 = csr[i], s1 = csr[i + 1], s2 = csr[i + 2], s3 = csr[i + 3];
                    short8 v0 = ROWL(s0), v1 = ROWL(s1), v2 = ROWL(s2), v3 = ROWL(s3);
                    int c0 = csr[i + 4], c1 = csr[i + 5], c2 = csr[i + 6], c3 = csr[i + 7];
                    i += 8;
#pragma unroll 2
                    for (; i + 3 < end; i += 4) {
                        // issue batch B rows + batch C csr BEFORE consuming A
                        short8 w0 = ROWL(c0), w1 = ROWL(c1), w2 = ROWL(c2), w3 = ROWL(c3);
                        int n0 = csr[i], n1 = csr[i + 1], n2 = csr[i + 2], n3 = csr[i + 3];
#pragma unroll
                        for (int j = 0; j < 8; j++) {
                            a0[j] += b2f((u16)v0[j]) + b2f((u16)v2[j]);
                            a1[j] += b2f((u16)v1[j]) + b2f((u16)v3[j]);
                        }
                        v0 = w0; v1 = w1; v2 = w2; v3 = w3;
                        c0 = n0; c1 = n1; c2 = n2; c3 = n3;
                    }
                    // drain A
#pragma unroll
                    for (int j = 0; j < 8; j++) {
                        a0[j] += b2f((u16)v0[j]) + b2f((u16)v2[j]);
                        a1[j] += b2f((u16)v1[j]) + b2f((u16)v3[j]);
                    }
                    // drain B
                    {
                        short8 w0 = ROWL(c0), w1 = ROWL(c1), w2 = ROWL(c2), w3 = ROWL(c3);
#pragma unroll
                        for (int j = 0; j < 8; j++) {
                            a0[j] += b2f((u16)w0[j]) + b2f((u16)w2[j]);
                            a1[j] += b2f((u16)w1[j]) + b2f((u16)w3[j]);
                        }
                    }
                } else {
                    for (; i + 3 < end; i += 4) {
                        int s0 = csr[i], s1 = csr[i + 1], s2 = csr[i + 2], s3 = csr[i + 3];
                        short8 v0 = ROWL(s0), v1 = ROWL(s1), v2 = ROWL(s2), v3 = ROWL(s3);
#pragma unroll
                        for (int j = 0; j < 8; j++) {
                            a0[j] += b2f((u16)v0[j]) + b2f((u16)v2[j]);
                            a1[j] += b2f((u16)v1[j]) + b2f((u16)v3[j]);
                        }
                    }
                }
                for (; i < end; i++) {
                    int s0 = csr[i];
                    short8 v0 = ROWL(s0);
#pragma unroll
                    for (int j = 0; j < 8; j++) a0[j] += b2f((u16)v0[j]);
                }
            }
            short8 o;
#pragma unroll
            for (int j = 0; j < 8; j++)
                o[j] = (short)f2b(fmaxf(a0[j] + a1[j] + bb[j], 0.f));
            *(short8*)&A[lrow][c * 8] = o;
        }
#undef ROWL
    }
    __syncthreads();

    // ---- phase 2: MFMA from LDS
    const int wave = tid >> 6;           // 0..7
    const int lane = tid & 63;
    const int m = lane & 15;
    const int q = lane >> 4;
    const int rg = wave & 3;             // row group (16 rows)
    const int ch = wave >> 2;            // col half
    const int lrow = rg * 16 + m;

    short8 af[4];
#pragma unroll
    for (int kt = 0; kt < 4; kt++)
        af[kt] = *(const short8*)&A[lrow][kt * 32 + q * 8];

    constexpr int NTH = (NT + 1) / 2;
    const int ntB = ch ? NTH : 0;
    const int ntE = ch ? NT : NTH;

    f32x4 acc[NTH];
#pragma unroll
    for (int i = 0; i < NTH; i++) acc[i] = (f32x4)0.f;

#pragma unroll
    for (int kt = 0; kt < 4; kt++) {
        for (int nt = ntB; nt < ntE; nt++) {
            short8 bf = *(const short8*)(Wf + (size_t)((nt * 4 + kt) * 64 + lane) * 8);
            acc[nt - ntB] = __builtin_amdgcn_mfma_f32_16x16x32_bf16(af[kt], bf, acc[nt - ntB], 0, 0, 0);
        }
    }

    for (int nt = ntB; nt < ntE; nt++) {
        const int col = nt * 16 + m;
        if (col < OCOLS) {
#pragma unroll
            for (int r = 0; r < 4; r++) {
                int orow = rowBase + rg * 16 + q * 4 + r;
                if (orow < N) out[(size_t)orow * OSTRIDE + col] = f2b(acc[nt - ntB][r]);
            }
        }
    }
}

// ---------------------------------------------------------------------------
// K6: aggregate first 40 feats of bf16 stride-40 rows, + b2 -> fp32 d_out
// stride 40 -> 4.0 MB working set ~= per-XCD L2
// ---------------------------------------------------------------------------
__global__ __launch_bounds__(256) void agg40b(
    const u16* __restrict__ val, const int* __restrict__ off,
    const int* __restrict__ csr, const float* __restrict__ b2,
    float* __restrict__ out, int N)
{
    const int c = threadIdx.x & 15;
    const int node = blockIdx.x * 16 + (threadIdx.x >> 4);
    if (node >= N || c >= 10) return;
    const int beg = off[node], end = off[node + 1];

    float a0[4] = {0, 0, 0, 0};
    float a1[4] = {0, 0, 0, 0};
    int i = beg;
    for (; i + 1 < end; i += 2) {
        int s0 = csr[i];
        int s1 = csr[i + 1];
        ushort4v v0 = *(const ushort4v*)(val + (size_t)s0 * 40 + c * 4);
        ushort4v v1 = *(const ushort4v*)(val + (size_t)s1 * 40 + c * 4);
        a0[0] += b2f(v0.x); a0[1] += b2f(v0.y); a0[2] += b2f(v0.z); a0[3] += b2f(v0.w);
        a1[0] += b2f(v1.x); a1[1] += b2f(v1.y); a1[2] += b2f(v1.z); a1[3] += b2f(v1.w);
    }
    if (i < end) {
        int s0 = csr[i];
        ushort4v v0 = *(const ushort4v*)(val + (size_t)s0 * 40 + c * 4);
        a0[0] += b2f(v0.x); a0[1] += b2f(v0.y); a0[2] += b2f(v0.z); a0[3] += b2f(v0.w);
    }
    float4 b = *(const float4*)(b2 + c * 4);
    float4 r;
    r.x = a0[0] + a1[0] + b.x;
    r.y = a0[1] + a1[1] + b.y;
    r.z = a0[2] + a1[2] + b.z;
    r.w = a0[3] + a1[3] + b.w;
    *(float4*)(out + (size_t)node * 40 + c * 4) = r;
}

extern "C" void kernel_launch(void* const* d_in, const int* in_sizes, int n_in,
                              void* d_out, int out_size, void* d_ws, size_t ws_size,
                              hipStream_t stream)
{
    const float* x  = (const float*)d_in[0];
    const int*   ei = (const int*)d_in[1];
    const float* W0 = (const float*)d_in[2];
    const float* b0 = (const float*)d_in[3];
    const float* W1 = (const float*)d_in[4];
    const float* b1 = (const float*)d_in[5];
    const float* W2 = (const float*)d_in[6];
    const float* b2 = (const float*)d_in[7];
    float* out = (float*)d_out;

    const int N = NN, E = EE;
    const int* src = ei;        // edge_index[0]
    const int* dst = ei + E;    // edge_index[1]

    char* ws = (char*)d_ws;
    u16* t     = (u16*)ws;                          // 12.8 MB (layer-0 GEMM out)
    u16* tB    = (u16*)(ws + 12800000);             // 12.8 MB (layer-1 fused out)
    u16* t2    = (u16*)(ws + 25600000);             // 4.0 MB (layer-2, stride 40)
    u16* Wf    = (u16*)(ws + 29600000);             // 96 KB (frag-packed W)
    int* off   = (int*)(ws + 29700000);             // 200 KB (N+1)
    int* csr   = (int*)(ws + 29900008);             // 3.2 MB
    int* gCur  = (int*)(ws + 33100008);             // 784 B (bucket cursors)
    u32* pairs = (u32*)(ws + 33100800);             // 4.82 MB (196*6144*4)

    const int tileGrid = (N + 63) / 64;             // 782
    const int agg40Grid = (N + 15) / 16;            // 3125

    // K1: weight packing + bucket-cursor init
    prep_init<<<25, 256, 0, stream>>>(W0, W1, W2, Wf, gCur);
    // K2: batch-reserved scatter + layer-0 GEMM (independent, one launch)
    scatter_gemm0<<<GB + tileGrid, 256, 0, stream>>>(src, dst, gCur, pairs,
                                                     x, Wf, t, N, E);
    // K3: per-bucket sort -> off[] + csr[]
    bucket_sort<<<BKT, 256, 0, stream>>>(pairs, gCur, off, csr, N, E);

    // K4: layer 1 fused: tB = relu(agg(t) + b0) @ W1
    agg_gemm_t<8, 128, 128><<<tileGrid, 512, 0, stream>>>(t, off, csr, b0,
                                                          Wf + 16384, tB, N);
    // K5: layer 2 fused: t2 = relu(agg(tB) + b1) @ W2pad, 40 true cols
    agg_gemm_t<3, 40, 40><<<tileGrid, 512, 0, stream>>>(tB, off, csr, b1,
                                                        Wf + 32768, t2, N);
    // K6: out = agg40(t2) + b2
    agg40b<<<agg40Grid, 256, 0, stream>>>(t2, off, csr, b2, out, N);
}

// Round 5
// 210.761 us; speedup vs baseline: 1.0925x; 1.0925x over previous
//
#include <hip/hip_runtime.h>

#define NN 50000
#define EE 800000

#define BKT 196      // buckets = dst>>8 (256 nodes each)
#define GB  334      // scatter blocks
#define EPB 2396     // edges per block (334*2396 = 800264 >= E)
#define CAPB 6144    // fixed bucket capacity (mean 4096, +32 sigma)
#define CAP 5120     // LDS staging capacity in bucket_sort

typedef unsigned char u8;
typedef unsigned short u16;
typedef unsigned int u32;
typedef __attribute__((ext_vector_type(8))) short short8;   // 8 bf16 (4 VGPRs)
typedef __attribute__((ext_vector_type(4))) float f32x4;
typedef __attribute__((ext_vector_type(2))) float f32x2;
typedef __attribute__((ext_vector_type(2))) unsigned int u32x2;
typedef __attribute__((ext_vector_type(4))) unsigned short ushort4v;

__device__ __forceinline__ float b2f(u16 u) {
    return __uint_as_float(((unsigned)u) << 16);
}
__device__ __forceinline__ u16 f2b(float f) {
    unsigned u = __float_as_uint(f);
    return (u16)((u + 0x7FFF + ((u >> 16) & 1)) >> 16);   // RNE
}

// ---------------- fp8 e4m3 encode/decode (HW cvt on gfx950; sw fallback) ----
#if defined(__has_builtin)
#if __has_builtin(__builtin_amdgcn_cvt_pk_f32_fp8) && __has_builtin(__builtin_amdgcn_cvt_pk_fp8_f32)
#define HW_FP8 1
#endif
#endif

#ifdef HW_FP8
__device__ __forceinline__ void dec4(u32 w, float* f) {
    f32x2 lo = __builtin_amdgcn_cvt_pk_f32_fp8(w, false);
    f32x2 hi = __builtin_amdgcn_cvt_pk_f32_fp8(w, true);
    f[0] = lo[0]; f[1] = lo[1]; f[2] = hi[0]; f[3] = hi[1];
}
__device__ __forceinline__ u8 enc1(float v) {
    return (u8)(__builtin_amdgcn_cvt_pk_fp8_f32(v, v, 0, false) & 0xFF);
}
#else
// software e4m3fn: denormals flushed (|v|<2^-6 -> 0; bounded err 0.016/elem)
__device__ __forceinline__ float dec1(u8 b) {
    u32 m = b & 0x7F;
    if (m < 8) return 0.f;                       // denorm/zero flush
    u32 u = ((u32)(b & 0x80) << 24) | ((m + (120u << 3)) << 20);
    return __uint_as_float(u);
}
__device__ __forceinline__ void dec4(u32 w, float* f) {
    f[0] = dec1((u8)(w & 0xFF));
    f[1] = dec1((u8)((w >> 8) & 0xFF));
    f[2] = dec1((u8)((w >> 16) & 0xFF));
    f[3] = dec1((u8)((w >> 24) & 0xFF));
}
__device__ __forceinline__ u8 enc1(float v) {
    u32 u = __float_as_uint(v);
    u32 mag = u & 0x7FFFFFFF;
    if (mag < 0x3C800000u) return 0;             // < 2^-6 -> 0
    if (mag > 0x43E00000u) mag = 0x43E00000u;    // clamp 448
    u32 r = mag + 0x7FFFFu + ((mag >> 20) & 1);  // RNE at bit 20
    u32 e = (r >> 20) - (120u << 3);
    if (e > 0x7E) e = 0x7E;
    return (u8)(((u >> 24) & 0x80) | e);
}
#endif

__device__ __forceinline__ void dec8(u32x2 v, float* f) {
    dec4(v.x, f);
    dec4(v.y, f + 4);
}

// ---------------------------------------------------------------------------
// K1: blocks 0..23 pack W0/W1/W2(padded) into MFMA B-fragment order (bf16 --
//     weights/MFMA stay bf16; only gathered ACTIVATIONS are fp8);
//     block 24 inits the 196 global bucket cursors to b*CAPB.
// ---------------------------------------------------------------------------
__global__ __launch_bounds__(256) void prep_init(
    const float* __restrict__ W0, const float* __restrict__ W1,
    const float* __restrict__ W2, u16* __restrict__ Wf,
    int* __restrict__ gCur)
{
    const int g = blockIdx.x, t = threadIdx.x;
    if (g == 24) {
        if (t < BKT) gCur[t] = t * CAPB;
        return;
    }
    int u = g * 4 + (t >> 6);               // 0..95
    int set = u >> 5, nt2 = (u >> 2) & 7, kt = u & 3;
    int lane = t & 63;
    const float* W = (set == 0) ? W0 : (set == 1) ? W1 : W2;
    int ld = (set == 2) ? 40 : 128;
    int ncols = (set == 2) ? 40 : 128;
    int n = nt2 * 16 + (lane & 15);
    int kb = kt * 32 + (lane >> 4) * 8;
    u16* dw = Wf + set * 16384 + (size_t)((nt2 * 4 + kt) * 64 + lane) * 8;
#pragma unroll
    for (int j = 0; j < 8; j++) {
        float v = (n < ncols) ? W[(kb + j) * ld + n] : 0.f;
        dw[j] = f2b(v);
    }
}

// ---------------------------------------------------------------------------
// K2: blocks [0,GB): 2-pass scatter with atomic batch reservation.
//     blocks [GB,..): layer-0 GEMM  t = bf16(x) @ W0, OUTPUT STORED FP8.
// Rationale (R0-R4 evidence): gather phases are line-request-rate bound
// (invariant 46.8us across unroll/pipeline/column-split; ~34G lines/s).
// fp8 rows = 128B = 1 line/edge instead of 2.
// ---------------------------------------------------------------------------
__global__ __launch_bounds__(256) void scatter_gemm0(
    const int* __restrict__ src, const int* __restrict__ dst,
    int* __restrict__ gCur, u32* __restrict__ pairs,
    const float* __restrict__ A, const u16* __restrict__ Wf,
    u8* __restrict__ out, int N, int E)
{
    __shared__ int cnt[BKT];
    __shared__ int cur[BKT];
    const int t = threadIdx.x;
    if (blockIdx.x < GB) {
        const int g = blockIdx.x;
        for (int b = t; b < BKT; b += 256) cnt[b] = 0;
        __syncthreads();
        const int beg = g * EPB, end = min(E, beg + EPB);
        for (int e = beg + t; e < end; e += 256)
            atomicAdd(&cnt[dst[e] >> 8], 1);
        __syncthreads();
        for (int b = t; b < BKT; b += 256)
            cur[b] = atomicAdd(&gCur[b], cnt[b]);
        __syncthreads();
        for (int e = beg + t; e < end; e += 256) {
            int d = dst[e];
            int pos = atomicAdd(&cur[d >> 8], 1);
            pairs[pos] = ((u32)src[e] << 8) | (u32)(d & 255);
        }
        return;
    }
    // ---- gemm0 ----
    const int bx = blockIdx.x - GB;
    const int wave = t >> 6;
    const int lane = t & 63;
    const int m = lane & 15;
    const int q = lane >> 4;
    const int rowBase = bx * 64 + wave * 16;
    const int arow = rowBase + m;
    const bool rowOk = (arow < N);

    short8 af[4];
#pragma unroll
    for (int kt = 0; kt < 4; kt++) {
        if (rowOk) {
            float4 lo = *(const float4*)(A + (size_t)arow * 128 + kt * 32 + q * 8);
            float4 hi = *(const float4*)(A + (size_t)arow * 128 + kt * 32 + q * 8 + 4);
            short8 v;
            v[0] = (short)f2b(lo.x); v[1] = (short)f2b(lo.y);
            v[2] = (short)f2b(lo.z); v[3] = (short)f2b(lo.w);
            v[4] = (short)f2b(hi.x); v[5] = (short)f2b(hi.y);
            v[6] = (short)f2b(hi.z); v[7] = (short)f2b(hi.w);
            af[kt] = v;
        } else {
            af[kt] = (short8)0;
        }
    }

    f32x4 acc[8];
#pragma unroll
    for (int nt = 0; nt < 8; nt++) acc[nt] = (f32x4)0.f;

#pragma unroll
    for (int kt = 0; kt < 4; kt++) {
#pragma unroll
        for (int nt = 0; nt < 8; nt++) {
            short8 bf = *(const short8*)(Wf + (size_t)((nt * 4 + kt) * 64 + lane) * 8);
            acc[nt] = __builtin_amdgcn_mfma_f32_16x16x32_bf16(af[kt], bf, acc[nt], 0, 0, 0);
        }
    }

#pragma unroll
    for (int nt = 0; nt < 8; nt++) {
#pragma unroll
        for (int r = 0; r < 4; r++) {
            int orow = rowBase + q * 4 + r;
            if (orow < N) out[(size_t)orow * 128 + nt * 16 + m] = enc1(acc[nt][r]);
        }
    }
}

// ---------------------------------------------------------------------------
// K3: per-bucket node sort (round-0 256-key version; 2048-key variant was a
// measured regression, R1).
// ---------------------------------------------------------------------------
__global__ __launch_bounds__(256) void bucket_sort(
    const u32* __restrict__ pairs, const int* __restrict__ gCur,
    int* __restrict__ off, int* __restrict__ csr, int N, int E)
{
    __shared__ int sdeg[256];
    __shared__ int sex[256];
    __shared__ int scur[256];
    __shared__ int stage[CAP];
    const int b = blockIdx.x, t = threadIdx.x;

    int c0 = (t < BKT) ? (gCur[t] - t * CAPB) : 0;
    sex[t] = c0;
    __syncthreads();
    for (int d = 1; d < 256; d <<= 1) {
        int u = (t >= d) ? sex[t - d] : 0;
        __syncthreads();
        sex[t] += u;
        __syncthreads();
    }
    __shared__ int sBase, sCnt;
    if (t == b) { sBase = sex[t] - c0; sCnt = c0; }
    __syncthreads();
    const int base = sBase;
    const int cnt = sCnt;
    const int pbase = b * CAPB;
    __syncthreads();

    sdeg[t] = 0;
    __syncthreads();
    for (int i = t; i < cnt; i += 256)
        atomicAdd(&sdeg[pairs[pbase + i] & 255], 1);
    __syncthreads();

    int v = sdeg[t];
    sex[t] = v;
    __syncthreads();
    for (int d = 1; d < 256; d <<= 1) {
        int u = (t >= d) ? sex[t - d] : 0;
        __syncthreads();
        sex[t] += u;
        __syncthreads();
    }
    const int excl = sex[t] - v;
    const int node = b * 256 + t;
    if (node < N) off[node] = base + excl;
    if (b == BKT - 1 && t == 0) off[N] = E;
    scur[t] = excl;
    __syncthreads();

    if (cnt <= CAP) {
        for (int i = t; i < cnt; i += 256) {
            u32 p = pairs[pbase + i];
            int pos = atomicAdd(&scur[p & 255], 1);
            stage[pos] = (int)(p >> 8);
        }
        __syncthreads();
        for (int i = t; i < cnt; i += 256) csr[base + i] = stage[i];
    } else {
        for (int i = t; i < cnt; i += 256) {
            u32 p = pairs[pbase + i];
            int pos = atomicAdd(&scur[p & 255], 1);
            csr[base + pos] = (int)(p >> 8);
        }
    }
}

// ---------------------------------------------------------------------------
// K4/K5: FUSED layer: out = ( relu(agg(val_fp8) + bias) ) @ W
// block = 64 dst nodes, 512 threads (8 waves). R0 loop structure (unroll-4;
// SWP is compiler-defeated, R4; unroll-8 neutral, R1).
// phase 1: gather fp8 rows (128B = 1 line/edge), HW cvt_pk decode, f32
//          accumulate, bias+relu, bf16 -> LDS.
// phase 2: bf16 MFMA from LDS (weights bf16 -- unchanged numerics).
// OCOLS clamps stores to the true output width (stride-40 clobber bug, R11).
// OFP8: K4 stores tB as fp8 (gathered by K5); K5 stores t2 bf16 (K6 input,
// kept bf16 to limit quantization boundaries to two).
// NOTE: val and out MUST differ (cross-block gather; in-place is a race).
// ---------------------------------------------------------------------------
template<int NT, int OSTRIDE, int OCOLS, bool OFP8>
__global__ __launch_bounds__(512) void agg_gemm_t(
    const u8* __restrict__ val, const int* __restrict__ off,
    const int* __restrict__ csr, const float* __restrict__ bias,
    const u16* __restrict__ Wf, void* __restrict__ outp, int N)
{
    __shared__ u16 A[64][136];   // 17.4 KB
    const int tid = threadIdx.x;
    const int rowBase = blockIdx.x * 64;

    // ---- phase 1: aggregate fp8, bias+relu, bf16 -> LDS
    {
        const int c = tid & 15;          // 8-byte chunk (8 fp8 cols)
        const int nl = tid >> 4;         // 0..31
        const u8* vb = val + c * 8;
        float4 bA = *(const float4*)(bias + c * 8);
        float4 bB = *(const float4*)(bias + c * 8 + 4);
        float bb[8] = {bA.x, bA.y, bA.z, bA.w, bB.x, bB.y, bB.z, bB.w};
#define ROWL(s) (*(const u32x2*)(vb + (size_t)(s) * 128))
#pragma unroll
        for (int g = 0; g < 2; g++) {
            const int lrow = g * 32 + nl;
            const int node = rowBase + lrow;
            float a0[8] = {0, 0, 0, 0, 0, 0, 0, 0};
            float a1[8] = {0, 0, 0, 0, 0, 0, 0, 0};
            if (node < N) {
                const int beg = off[node], end = off[node + 1];
                int i = beg;
                for (; i + 3 < end; i += 4) {
                    int s0 = csr[i], s1 = csr[i + 1], s2 = csr[i + 2], s3 = csr[i + 3];
                    u32x2 v0 = ROWL(s0);
                    u32x2 v1 = ROWL(s1);
                    u32x2 v2 = ROWL(s2);
                    u32x2 v3 = ROWL(s3);
                    float f0[8], f1[8], f2[8], f3[8];
                    dec8(v0, f0); dec8(v1, f1); dec8(v2, f2); dec8(v3, f3);
#pragma unroll
                    for (int j = 0; j < 8; j++) {
                        a0[j] += f0[j] + f2[j];
                        a1[j] += f1[j] + f3[j];
                    }
                }
                for (; i < end; i++) {
                    int s0 = csr[i];
                    u32x2 v0 = ROWL(s0);
                    float f0[8];
                    dec8(v0, f0);
#pragma unroll
                    for (int j = 0; j < 8; j++) a0[j] += f0[j];
                }
            }
            short8 o;
#pragma unroll
            for (int j = 0; j < 8; j++)
                o[j] = (short)f2b(fmaxf(a0[j] + a1[j] + bb[j], 0.f));
            *(short8*)&A[lrow][c * 8] = o;
        }
#undef ROWL
    }
    __syncthreads();

    // ---- phase 2: MFMA from LDS
    const int wave = tid >> 6;           // 0..7
    const int lane = tid & 63;
    const int m = lane & 15;
    const int q = lane >> 4;
    const int rg = wave & 3;             // row group (16 rows)
    const int ch = wave >> 2;            // col half
    const int lrow = rg * 16 + m;

    short8 af[4];
#pragma unroll
    for (int kt = 0; kt < 4; kt++)
        af[kt] = *(const short8*)&A[lrow][kt * 32 + q * 8];

    constexpr int NTH = (NT + 1) / 2;
    const int ntB = ch ? NTH : 0;
    const int ntE = ch ? NT : NTH;

    f32x4 acc[NTH];
#pragma unroll
    for (int i = 0; i < NTH; i++) acc[i] = (f32x4)0.f;

#pragma unroll
    for (int kt = 0; kt < 4; kt++) {
        for (int nt = ntB; nt < ntE; nt++) {
            short8 bf = *(const short8*)(Wf + (size_t)((nt * 4 + kt) * 64 + lane) * 8);
            acc[nt - ntB] = __builtin_amdgcn_mfma_f32_16x16x32_bf16(af[kt], bf, acc[nt - ntB], 0, 0, 0);
        }
    }

    for (int nt = ntB; nt < ntE; nt++) {
        const int col = nt * 16 + m;
        if (col < OCOLS) {
#pragma unroll
            for (int r = 0; r < 4; r++) {
                int orow = rowBase + rg * 16 + q * 4 + r;
                if (orow < N) {
                    if constexpr (OFP8) {
                        ((u8*)outp)[(size_t)orow * OSTRIDE + col] = enc1(acc[nt - ntB][r]);
                    } else {
                        ((u16*)outp)[(size_t)orow * OSTRIDE + col] = f2b(acc[nt - ntB][r]);
                    }
                }
            }
        }
    }
}

// ---------------------------------------------------------------------------
// K6: aggregate first 40 feats of bf16 stride-40 rows, + b2 -> fp32 d_out
// (t2 kept bf16: limits fp8 quantization boundaries to t and tB)
// ---------------------------------------------------------------------------
__global__ __launch_bounds__(256) void agg40b(
    const u16* __restrict__ val, const int* __restrict__ off,
    const int* __restrict__ csr, const float* __restrict__ b2,
    float* __restrict__ out, int N)
{
    const int c = threadIdx.x & 15;
    const int node = blockIdx.x * 16 + (threadIdx.x >> 4);
    if (node >= N || c >= 10) return;
    const int beg = off[node], end = off[node + 1];

    float a0[4] = {0, 0, 0, 0};
    float a1[4] = {0, 0, 0, 0};
    int i = beg;
    for (; i + 1 < end; i += 2) {
        int s0 = csr[i];
        int s1 = csr[i + 1];
        ushort4v v0 = *(const ushort4v*)(val + (size_t)s0 * 40 + c * 4);
        ushort4v v1 = *(const ushort4v*)(val + (size_t)s1 * 40 + c * 4);
        a0[0] += b2f(v0.x); a0[1] += b2f(v0.y); a0[2] += b2f(v0.z); a0[3] += b2f(v0.w);
        a1[0] += b2f(v1.x); a1[1] += b2f(v1.y); a1[2] += b2f(v1.z); a1[3] += b2f(v1.w);
    }
    if (i < end) {
        int s0 = csr[i];
        ushort4v v0 = *(const ushort4v*)(val + (size_t)s0 * 40 + c * 4);
        a0[0] += b2f(v0.x); a0[1] += b2f(v0.y); a0[2] += b2f(v0.z); a0[3] += b2f(v0.w);
    }
    float4 b = *(const float4*)(b2 + c * 4);
    float4 r;
    r.x = a0[0] + a1[0] + b.x;
    r.y = a0[1] + a1[1] + b.y;
    r.z = a0[2] + a1[2] + b.z;
    r.w = a0[3] + a1[3] + b.w;
    *(float4*)(out + (size_t)node * 40 + c * 4) = r;
}

extern "C" void kernel_launch(void* const* d_in, const int* in_sizes, int n_in,
                              void* d_out, int out_size, void* d_ws, size_t ws_size,
                              hipStream_t stream)
{
    const float* x  = (const float*)d_in[0];
    const int*   ei = (const int*)d_in[1];
    const float* W0 = (const float*)d_in[2];
    const float* b0 = (const float*)d_in[3];
    const float* W1 = (const float*)d_in[4];
    const float* b1 = (const float*)d_in[5];
    const float* W2 = (const float*)d_in[6];
    const float* b2 = (const float*)d_in[7];
    float* out = (float*)d_out;

    const int N = NN, E = EE;
    const int* src = ei;        // edge_index[0]
    const int* dst = ei + E;    // edge_index[1]

    char* ws = (char*)d_ws;
    u8*  t     = (u8*)ws;                           // 6.4 MB (layer-0 out, fp8)
    u8*  tB    = (u8*)(ws + 6400000);               // 6.4 MB (layer-1 out, fp8)
    u16* t2    = (u16*)(ws + 12800000);             // 4.0 MB (layer-2, bf16 stride 40)
    u16* Wf    = (u16*)(ws + 16800000);             // 96 KB (frag-packed W, bf16)
    int* off   = (int*)(ws + 16900000);             // 200 KB (N+1)
    int* csr   = (int*)(ws + 17100008);             // 3.2 MB
    int* gCur  = (int*)(ws + 20300008);             // 784 B (bucket cursors)
    u32* pairs = (u32*)(ws + 20300800);             // 4.82 MB (196*6144*4)

    const int tileGrid = (N + 63) / 64;             // 782
    const int agg40Grid = (N + 15) / 16;            // 3125

    // K1: weight packing + bucket-cursor init
    prep_init<<<25, 256, 0, stream>>>(W0, W1, W2, Wf, gCur);
    // K2: batch-reserved scatter + layer-0 GEMM (fp8 out)
    scatter_gemm0<<<GB + tileGrid, 256, 0, stream>>>(src, dst, gCur, pairs,
                                                     x, Wf, t, N, E);
    // K3: per-bucket sort -> off[] + csr[]
    bucket_sort<<<BKT, 256, 0, stream>>>(pairs, gCur, off, csr, N, E);

    // K4: layer 1 fused: tB(fp8) = relu(agg(t_fp8) + b0) @ W1
    agg_gemm_t<8, 128, 128, true><<<tileGrid, 512, 0, stream>>>(
        t, off, csr, b0, Wf + 16384, (void*)tB, N);
    // K5: layer 2 fused: t2(bf16) = relu(agg(tB_fp8) + b1) @ W2pad, 40 cols
    agg_gemm_t<3, 40, 40, false><<<tileGrid, 512, 0, stream>>>(
        tB, off, csr, b1, Wf + 32768, (void*)t2, N);
    // K6: out = agg40(t2) + b2
    agg40b<<<agg40Grid, 256, 0, stream>>>(t2, off, csr, b2, out, N);
}

// Round 7
// 199.035 us; speedup vs baseline: 1.1569x; 1.0589x over previous
//
#include <hip/hip_runtime.h>

#define NN 50000
#define EE 800000

#define BKT 196      // buckets = dst>>8 (256 nodes each)
#define GB  334      // scatter blocks
#define EPB 2396     // edges per block (334*2396 = 800264 >= E)
#define CAPB 6144    // fixed bucket capacity (mean 4096, +32 sigma)
#define CAP 5120     // LDS staging capacity in bucket_sort

typedef unsigned char u8;
typedef unsigned short u16;
typedef unsigned int u32;
typedef __attribute__((ext_vector_type(8))) short short8;   // 8 bf16 (4 VGPRs)
typedef __attribute__((ext_vector_type(4))) float f32x4;
typedef __attribute__((ext_vector_type(2))) float f32x2;
typedef __attribute__((ext_vector_type(4))) unsigned int u32x4;
typedef __attribute__((ext_vector_type(4))) unsigned short ushort4v;

__device__ __forceinline__ float b2f(u16 u) {
    return __uint_as_float(((unsigned)u) << 16);
}
__device__ __forceinline__ u16 f2b(float f) {
    unsigned u = __float_as_uint(f);
    return (u16)((u + 0x7FFF + ((u >> 16) & 1)) >> 16);   // RNE
}

// ---------------- fp8 e4m3 encode/decode (HW cvt on gfx950; sw fallback) ----
#if defined(__has_builtin)
#if __has_builtin(__builtin_amdgcn_cvt_pk_f32_fp8) && __has_builtin(__builtin_amdgcn_cvt_pk_fp8_f32)
#define HW_FP8 1
#endif
#endif

#ifdef HW_FP8
__device__ __forceinline__ void dec4(u32 w, float* f) {
    f32x2 lo = __builtin_amdgcn_cvt_pk_f32_fp8(w, false);
    f32x2 hi = __builtin_amdgcn_cvt_pk_f32_fp8(w, true);
    f[0] = lo[0]; f[1] = lo[1]; f[2] = hi[0]; f[3] = hi[1];
}
__device__ __forceinline__ u8 enc1(float v) {
    return (u8)(__builtin_amdgcn_cvt_pk_fp8_f32(v, v, 0, false) & 0xFF);
}
#else
// software e4m3fn: denormals flushed (|v|<2^-6 -> 0; bounded err 0.016/elem)
__device__ __forceinline__ float dec1(u8 b) {
    u32 m = b & 0x7F;
    if (m < 8) return 0.f;                       // denorm/zero flush
    u32 u = ((u32)(b & 0x80) << 24) | ((m + (120u << 3)) << 20);
    return __uint_as_float(u);
}
__device__ __forceinline__ void dec4(u32 w, float* f) {
    f[0] = dec1((u8)(w & 0xFF));
    f[1] = dec1((u8)((w >> 8) & 0xFF));
    f[2] = dec1((u8)((w >> 16) & 0xFF));
    f[3] = dec1((u8)((w >> 24) & 0xFF));
}
__device__ __forceinline__ u8 enc1(float v) {
    u32 u = __float_as_uint(v);
    u32 mag = u & 0x7FFFFFFF;
    if (mag < 0x3C800000u) return 0;             // < 2^-6 -> 0
    if (mag > 0x43E00000u) mag = 0x43E00000u;    // clamp 448
    u32 r = mag + 0x7FFFFu + ((mag >> 20) & 1);  // RNE at bit 20
    u32 e = (r >> 20) - (120u << 3);
    if (e > 0x7E) e = 0x7E;
    return (u8)(((u >> 24) & 0x80) | e);
}
#endif

__device__ __forceinline__ void dec16(u32x4 v, float* f) {
    dec4(v.x, f);
    dec4(v.y, f + 4);
    dec4(v.z, f + 8);
    dec4(v.w, f + 12);
}

// ---------------------------------------------------------------------------
// K1: blocks 0..23 pack W0/W1/W2(padded) into MFMA B-fragment order (bf16 --
//     weights/MFMA stay bf16; only gathered ACTIVATIONS are fp8);
//     block 24 inits the 196 global bucket cursors to b*CAPB.
// ---------------------------------------------------------------------------
__global__ __launch_bounds__(256) void prep_init(
    const float* __restrict__ W0, const float* __restrict__ W1,
    const float* __restrict__ W2, u16* __restrict__ Wf,
    int* __restrict__ gCur)
{
    const int g = blockIdx.x, t = threadIdx.x;
    if (g == 24) {
        if (t < BKT) gCur[t] = t * CAPB;
        return;
    }
    int u = g * 4 + (t >> 6);               // 0..95
    int set = u >> 5, nt2 = (u >> 2) & 7, kt = u & 3;
    int lane = t & 63;
    const float* W = (set == 0) ? W0 : (set == 1) ? W1 : W2;
    int ld = (set == 2) ? 40 : 128;
    int ncols = (set == 2) ? 40 : 128;
    int n = nt2 * 16 + (lane & 15);
    int kb = kt * 32 + (lane >> 4) * 8;
    u16* dw = Wf + set * 16384 + (size_t)((nt2 * 4 + kt) * 64 + lane) * 8;
#pragma unroll
    for (int j = 0; j < 8; j++) {
        float v = (n < ncols) ? W[(kb + j) * ld + n] : 0.f;
        dw[j] = f2b(v);
    }
}

// ---------------------------------------------------------------------------
// K2: blocks [0,GB): 2-pass scatter with atomic batch reservation.
//     blocks [GB,..): layer-0 GEMM  t = bf16(x) @ W0, OUTPUT STORED FP8.
// fp8 rows (128B) enable the 8-lane/row gather map in K4/K5 (request halving).
// ---------------------------------------------------------------------------
__global__ __launch_bounds__(256) void scatter_gemm0(
    const int* __restrict__ src, const int* __restrict__ dst,
    int* __restrict__ gCur, u32* __restrict__ pairs,
    const float* __restrict__ A, const u16* __restrict__ Wf,
    u8* __restrict__ out, int N, int E)
{
    __shared__ int cnt[BKT];
    __shared__ int cur[BKT];
    const int t = threadIdx.x;
    if (blockIdx.x < GB) {
        const int g = blockIdx.x;
        for (int b = t; b < BKT; b += 256) cnt[b] = 0;
        __syncthreads();
        const int beg = g * EPB, end = min(E, beg + EPB);
        for (int e = beg + t; e < end; e += 256)
            atomicAdd(&cnt[dst[e] >> 8], 1);
        __syncthreads();
        for (int b = t; b < BKT; b += 256)
            cur[b] = atomicAdd(&gCur[b], cnt[b]);
        __syncthreads();
        for (int e = beg + t; e < end; e += 256) {
            int d = dst[e];
            int pos = atomicAdd(&cur[d >> 8], 1);
            pairs[pos] = ((u32)src[e] << 8) | (u32)(d & 255);
        }
        return;
    }
    // ---- gemm0 ----
    const int bx = blockIdx.x - GB;
    const int wave = t >> 6;
    const int lane = t & 63;
    const int m = lane & 15;
    const int q = lane >> 4;
    const int rowBase = bx * 64 + wave * 16;
    const int arow = rowBase + m;
    const bool rowOk = (arow < N);

    short8 af[4];
#pragma unroll
    for (int kt = 0; kt < 4; kt++) {
        if (rowOk) {
            float4 lo = *(const float4*)(A + (size_t)arow * 128 + kt * 32 + q * 8);
            float4 hi = *(const float4*)(A + (size_t)arow * 128 + kt * 32 + q * 8 + 4);
            short8 v;
            v[0] = (short)f2b(lo.x); v[1] = (short)f2b(lo.y);
            v[2] = (short)f2b(lo.z); v[3] = (short)f2b(lo.w);
            v[4] = (short)f2b(hi.x); v[5] = (short)f2b(hi.y);
            v[6] = (short)f2b(hi.z); v[7] = (short)f2b(hi.w);
            af[kt] = v;
        } else {
            af[kt] = (short8)0;
        }
    }

    f32x4 acc[8];
#pragma unroll
    for (int nt = 0; nt < 8; nt++) acc[nt] = (f32x4)0.f;

#pragma unroll
    for (int kt = 0; kt < 4; kt++) {
#pragma unroll
        for (int nt = 0; nt < 8; nt++) {
            short8 bf = *(const short8*)(Wf + (size_t)((nt * 4 + kt) * 64 + lane) * 8);
            acc[nt] = __builtin_amdgcn_mfma_f32_16x16x32_bf16(af[kt], bf, acc[nt], 0, 0, 0);
        }
    }

#pragma unroll
    for (int nt = 0; nt < 8; nt++) {
#pragma unroll
        for (int r = 0; r < 4; r++) {
            int orow = rowBase + q * 4 + r;
            if (orow < N) out[(size_t)orow * 128 + nt * 16 + m] = enc1(acc[nt][r]);
        }
    }
}

// ---------------------------------------------------------------------------
// K3: per-bucket node sort (round-0 256-key version; 2048-key variant was a
// measured regression, R1).
// ---------------------------------------------------------------------------
__global__ __launch_bounds__(256) void bucket_sort(
    const u32* __restrict__ pairs, const int* __restrict__ gCur,
    int* __restrict__ off, int* __restrict__ csr, int N, int E)
{
    __shared__ int sdeg[256];
    __shared__ int sex[256];
    __shared__ int scur[256];
    __shared__ int stage[CAP];
    const int b = blockIdx.x, t = threadIdx.x;

    int c0 = (t < BKT) ? (gCur[t] - t * CAPB) : 0;
    sex[t] = c0;
    __syncthreads();
    for (int d = 1; d < 256; d <<= 1) {
        int u = (t >= d) ? sex[t - d] : 0;
        __syncthreads();
        sex[t] += u;
        __syncthreads();
    }
    __shared__ int sBase, sCnt;
    if (t == b) { sBase = sex[t] - c0; sCnt = c0; }
    __syncthreads();
    const int base = sBase;
    const int cnt = sCnt;
    const int pbase = b * CAPB;
    __syncthreads();

    sdeg[t] = 0;
    __syncthreads();
    for (int i = t; i < cnt; i += 256)
        atomicAdd(&sdeg[pairs[pbase + i] & 255], 1);
    __syncthreads();

    int v = sdeg[t];
    sex[t] = v;
    __syncthreads();
    for (int d = 1; d < 256; d <<= 1) {
        int u = (t >= d) ? sex[t - d] : 0;
        __syncthreads();
        sex[t] += u;
        __syncthreads();
    }
    const int excl = sex[t] - v;
    const int node = b * 256 + t;
    if (node < N) off[node] = base + excl;
    if (b == BKT - 1 && t == 0) off[N] = E;
    scur[t] = excl;
    __syncthreads();

    if (cnt <= CAP) {
        for (int i = t; i < cnt; i += 256) {
            u32 p = pairs[pbase + i];
            int pos = atomicAdd(&scur[p & 255], 1);
            stage[pos] = (int)(p >> 8);
        }
        __syncthreads();
        for (int i = t; i < cnt; i += 256) csr[base + i] = stage[i];
    } else {
        for (int i = t; i < cnt; i += 256) {
            u32 p = pairs[pbase + i];
            int pos = atomicAdd(&scur[p & 255], 1);
            csr[base + pos] = (int)(p >> 8);
        }
    }
}

// ---------------------------------------------------------------------------
// K4/K5: FUSED layer: out = ( relu(agg(val_fp8) + bias) ) @ W
// block = 64 dst nodes, 512 threads (8 waves).
// phase 1: 8-LANE/ROW gather (the R6 change). A 128B fp8 row = 8 lanes x 16B:
//   c8 = tid&7 (16B chunk = 16 fp8 cols), nl = tid>>3 (row 0..63, ONE pass).
//   vs R5's 16-lane map this HALVES VMEM instructions per edge (8 lane-reqs
//   instead of 16) and cuts the wave's serial chain ~1.8x (one pass over
//   max-degree-of-8 instead of two passes over max-degree-of-4). R0-R5
//   established the gather is request/serial-chain bound: time invariant to
//   issue structure, cache footprint, line count, and bytes/edge.
// phase 2: bf16 MFMA from LDS (weights bf16 -- unchanged numerics).
// OCOLS clamps stores to the true output width (stride-40 clobber bug, R11).
// OFP8: K4 stores tB as fp8 (gathered by K5); K5 stores t2 bf16 (K6 input).
// NOTE: val and out MUST differ (cross-block gather; in-place is a race).
// ---------------------------------------------------------------------------
template<int NT, int OSTRIDE, int OCOLS, bool OFP8>
__global__ __launch_bounds__(512) void agg_gemm_t(
    const u8* __restrict__ val, const int* __restrict__ off,
    const int* __restrict__ csr, const float* __restrict__ bias,
    const u16* __restrict__ Wf, void* __restrict__ outp, int N)
{
    __shared__ u16 A[64][136];   // 17.4 KB
    const int tid = threadIdx.x;
    const int rowBase = blockIdx.x * 64;

    // ---- phase 1: aggregate fp8 (8 lanes/row, 16B/lane), bias+relu -> LDS
    {
        const int c8 = tid & 7;          // 16B chunk (16 fp8 cols)
        const int nl = tid >> 3;         // 0..63 (all rows, one pass)
        const u8* vb = val + c8 * 16;
        const int node = rowBase + nl;
        const bool ok = (node < N);
        const int beg = ok ? off[node] : 0;
        const int end = ok ? off[node + 1] : 0;

        float a0[16], a1[16];
#pragma unroll
        for (int j = 0; j < 16; j++) { a0[j] = 0.f; a1[j] = 0.f; }

        int i = beg;
        for (; i + 3 < end; i += 4) {
            int s0 = csr[i], s1 = csr[i + 1], s2 = csr[i + 2], s3 = csr[i + 3];
            u32x4 v0 = *(const u32x4*)(vb + (size_t)s0 * 128);
            u32x4 v1 = *(const u32x4*)(vb + (size_t)s1 * 128);
            u32x4 v2 = *(const u32x4*)(vb + (size_t)s2 * 128);
            u32x4 v3 = *(const u32x4*)(vb + (size_t)s3 * 128);
            float f0[16], f1[16], f2[16], f3[16];
            dec16(v0, f0); dec16(v1, f1); dec16(v2, f2); dec16(v3, f3);
#pragma unroll
            for (int j = 0; j < 16; j++) {
                a0[j] += f0[j] + f2[j];
                a1[j] += f1[j] + f3[j];
            }
        }
        for (; i < end; i++) {
            int s0 = csr[i];
            u32x4 v0 = *(const u32x4*)(vb + (size_t)s0 * 128);
            float f0[16];
            dec16(v0, f0);
#pragma unroll
            for (int j = 0; j < 16; j++) a0[j] += f0[j];
        }

        float4 bA = *(const float4*)(bias + c8 * 16);
        float4 bB = *(const float4*)(bias + c8 * 16 + 4);
        float4 bC = *(const float4*)(bias + c8 * 16 + 8);
        float4 bD = *(const float4*)(bias + c8 * 16 + 12);
        float bb[16] = {bA.x, bA.y, bA.z, bA.w, bB.x, bB.y, bB.z, bB.w,
                        bC.x, bC.y, bC.z, bC.w, bD.x, bD.y, bD.z, bD.w};
        short8 o0, o1;
#pragma unroll
        for (int j = 0; j < 8; j++)
            o0[j] = (short)f2b(fmaxf(a0[j] + a1[j] + bb[j], 0.f));
#pragma unroll
        for (int j = 0; j < 8; j++)
            o1[j] = (short)f2b(fmaxf(a0[j + 8] + a1[j + 8] + bb[j + 8], 0.f));
        *(short8*)&A[nl][c8 * 16] = o0;
        *(short8*)&A[nl][c8 * 16 + 8] = o1;
    }
    __syncthreads();

    // ---- phase 2: MFMA from LDS
    const int wave = tid >> 6;           // 0..7
    const int lane = tid & 63;
    const int m = lane & 15;
    const int q = lane >> 4;
    const int rg = wave & 3;             // row group (16 rows)
    const int ch = wave >> 2;            // col half
    const int lrow = rg * 16 + m;

    short8 af[4];
#pragma unroll
    for (int kt = 0; kt < 4; kt++)
        af[kt] = *(const short8*)&A[lrow][kt * 32 + q * 8];

    constexpr int NTH = (NT + 1) / 2;
    const int ntB = ch ? NTH : 0;
    const int ntE = ch ? NT : NTH;

    f32x4 acc[NTH];
#pragma unroll
    for (int i = 0; i < NTH; i++) acc[i] = (f32x4)0.f;

#pragma unroll
    for (int kt = 0; kt < 4; kt++) {
        for (int nt = ntB; nt < ntE; nt++) {
            short8 bf = *(const short8*)(Wf + (size_t)((nt * 4 + kt) * 64 + lane) * 8);
            acc[nt - ntB] = __builtin_amdgcn_mfma_f32_16x16x32_bf16(af[kt], bf, acc[nt - ntB], 0, 0, 0);
        }
    }

    for (int nt = ntB; nt < ntE; nt++) {
        const int col = nt * 16 + m;
        if (col < OCOLS) {
#pragma unroll
            for (int r = 0; r < 4; r++) {
                int orow = rowBase + rg * 16 + q * 4 + r;
                if (orow < N) {
                    if constexpr (OFP8) {
                        ((u8*)outp)[(size_t)orow * OSTRIDE + col] = enc1(acc[nt - ntB][r]);
                    } else {
                        ((u16*)outp)[(size_t)orow * OSTRIDE + col] = f2b(acc[nt - ntB][r]);
                    }
                }
            }
        }
    }
}

// ---------------------------------------------------------------------------
// K6: aggregate first 40 feats of bf16 stride-40 rows, + b2 -> fp32 d_out
// (t2 kept bf16: limits fp8 quantization boundaries to t and tB)
// ---------------------------------------------------------------------------
__global__ __launch_bounds__(256) void agg40b(
    const u16* __restrict__ val, const int* __restrict__ off,
    const int* __restrict__ csr, const float* __restrict__ b2,
    float* __restrict__ out, int N)
{
    const int c = threadIdx.x & 15;
    const int node = blockIdx.x * 16 + (threadIdx.x >> 4);
    if (node >= N || c >= 10) return;
    const int beg = off[node], end = off[node + 1];

    float a0[4] = {0, 0, 0, 0};
    float a1[4] = {0, 0, 0, 0};
    int i = beg;
    for (; i + 1 < end; i += 2) {
        int s0 = csr[i];
        int s1 = csr[i + 1];
        ushort4v v0 = *(const ushort4v*)(val + (size_t)s0 * 40 + c * 4);
        ushort4v v1 = *(const ushort4v*)(val + (size_t)s1 * 40 + c * 4);
        a0[0] += b2f(v0.x); a0[1] += b2f(v0.y); a0[2] += b2f(v0.z); a0[3] += b2f(v0.w);
        a1[0] += b2f(v1.x); a1[1] += b2f(v1.y); a1[2] += b2f(v1.z); a1[3] += b2f(v1.w);
    }
    if (i < end) {
        int s0 = csr[i];
        ushort4v v0 = *(const ushort4v*)(val + (size_t)s0 * 40 + c * 4);
        a0[0] += b2f(v0.x); a0[1] += b2f(v0.y); a0[2] += b2f(v0.z); a0[3] += b2f(v0.w);
    }
    float4 b = *(const float4*)(b2 + c * 4);
    float4 r;
    r.x = a0[0] + a1[0] + b.x;
    r.y = a0[1] + a1[1] + b.y;
    r.z = a0[2] + a1[2] + b.z;
    r.w = a0[3] + a1[3] + b.w;
    *(float4*)(out + (size_t)node * 40 + c * 4) = r;
}

extern "C" void kernel_launch(void* const* d_in, const int* in_sizes, int n_in,
                              void* d_out, int out_size, void* d_ws, size_t ws_size,
                              hipStream_t stream)
{
    const float* x  = (const float*)d_in[0];
    const int*   ei = (const int*)d_in[1];
    const float* W0 = (const float*)d_in[2];
    const float* b0 = (const float*)d_in[3];
    const float* W1 = (const float*)d_in[4];
    const float* b1 = (const float*)d_in[5];
    const float* W2 = (const float*)d_in[6];
    const float* b2 = (const float*)d_in[7];
    float* out = (float*)d_out;

    const int N = NN, E = EE;
    const int* src = ei;        // edge_index[0]
    const int* dst = ei + E;    // edge_index[1]

    char* ws = (char*)d_ws;
    u8*  t     = (u8*)ws;                           // 6.4 MB (layer-0 out, fp8)
    u8*  tB    = (u8*)(ws + 6400000);               // 6.4 MB (layer-1 out, fp8)
    u16* t2    = (u16*)(ws + 12800000);             // 4.0 MB (layer-2, bf16 stride 40)
    u16* Wf    = (u16*)(ws + 16800000);             // 96 KB (frag-packed W, bf16)
    int* off   = (int*)(ws + 16900000);             // 200 KB (N+1)
    int* csr   = (int*)(ws + 17100008);             // 3.2 MB
    int* gCur  = (int*)(ws + 20300008);             // 784 B (bucket cursors)
    u32* pairs = (u32*)(ws + 20300800);             // 4.82 MB (196*6144*4)

    const int tileGrid = (N + 63) / 64;             // 782
    const int agg40Grid = (N + 15) / 16;            // 3125

    // K1: weight packing + bucket-cursor init
    prep_init<<<25, 256, 0, stream>>>(W0, W1, W2, Wf, gCur);
    // K2: batch-reserved scatter + layer-0 GEMM (fp8 out)
    scatter_gemm0<<<GB + tileGrid, 256, 0, stream>>>(src, dst, gCur, pairs,
                                                     x, Wf, t, N, E);
    // K3: per-bucket sort -> off[] + csr[]
    bucket_sort<<<BKT, 256, 0, stream>>>(pairs, gCur, off, csr, N, E);

    // K4: layer 1 fused: tB(fp8) = relu(agg(t_fp8) + b0) @ W1
    agg_gemm_t<8, 128, 128, true><<<tileGrid, 512, 0, stream>>>(
        t, off, csr, b0, Wf + 16384, (void*)tB, N);
    // K5: layer 2 fused: t2(bf16) = relu(agg(tB_fp8) + b1) @ W2pad, 40 cols
    agg_gemm_t<3, 40, 40, false><<<tileGrid, 512, 0, stream>>>(
        tB, off, csr, b1, Wf + 32768, (void*)t2, N);
    // K6: out = agg40(t2) + b2
    agg40b<<<agg40Grid, 256, 0, stream>>>(t2, off, csr, b2, out, N);
}

// Round 12
// 191.852 us; speedup vs baseline: 1.2002x; 1.0374x over previous
//
#include <hip/hip_runtime.h>

#define NN 50000
#define EE 800000

#define BKT 196      // buckets = dst>>8 (256 nodes each)
#define GB  334      // scatter blocks
#define EPB 2396     // edges per block (334*2396 = 800264 >= E)
#define CAPB 6144    // fixed bucket capacity (mean 4096, +32 sigma)
#define CAP 5120     // LDS staging capacity in bucket_sort
#define ECAP 1536    // per-block csr LDS cap in agg_gemm (mean 1024, +16 sigma)
#define ECAP6 512    // per-block csr LDS cap in agg40b (mean 256)

typedef unsigned char u8;
typedef unsigned short u16;
typedef unsigned int u32;
typedef __attribute__((ext_vector_type(8))) short short8;   // 8 bf16 (4 VGPRs)
typedef __attribute__((ext_vector_type(4))) float f32x4;
typedef __attribute__((ext_vector_type(2))) float f32x2;
typedef __attribute__((ext_vector_type(4))) unsigned int u32x4;
typedef __attribute__((ext_vector_type(4))) unsigned short ushort4v;

__device__ __forceinline__ float b2f(u16 u) {
    return __uint_as_float(((unsigned)u) << 16);
}
__device__ __forceinline__ u16 f2b(float f) {
    unsigned u = __float_as_uint(f);
    return (u16)((u + 0x7FFF + ((u >> 16) & 1)) >> 16);   // RNE
}

// ---------------- fp8 e4m3 encode/decode (HW cvt on gfx950; sw fallback) ----
#if defined(__has_builtin)
#if __has_builtin(__builtin_amdgcn_cvt_pk_f32_fp8) && __has_builtin(__builtin_amdgcn_cvt_pk_fp8_f32)
#define HW_FP8 1
#endif
#endif

#ifdef HW_FP8
__device__ __forceinline__ void dec4(u32 w, float* f) {
    f32x2 lo = __builtin_amdgcn_cvt_pk_f32_fp8(w, false);
    f32x2 hi = __builtin_amdgcn_cvt_pk_f32_fp8(w, true);
    f[0] = lo[0]; f[1] = lo[1]; f[2] = hi[0]; f[3] = hi[1];
}
__device__ __forceinline__ u8 enc1(float v) {
    return (u8)(__builtin_amdgcn_cvt_pk_fp8_f32(v, v, 0, false) & 0xFF);
}
#else
// software e4m3fn: denormals flushed (|v|<2^-6 -> 0; bounded err 0.016/elem)
__device__ __forceinline__ float dec1(u8 b) {
    u32 m = b & 0x7F;
    if (m < 8) return 0.f;                       // denorm/zero flush
    u32 u = ((u32)(b & 0x80) << 24) | ((m + (120u << 3)) << 20);
    return __uint_as_float(u);
}
__device__ __forceinline__ void dec4(u32 w, float* f) {
    f[0] = dec1((u8)(w & 0xFF));
    f[1] = dec1((u8)((w >> 8) & 0xFF));
    f[2] = dec1((u8)((w >> 16) & 0xFF));
    f[3] = dec1((u8)((w >> 24) & 0xFF));
}
__device__ __forceinline__ u8 enc1(float v) {
    u32 u = __float_as_uint(v);
    u32 mag = u & 0x7FFFFFFF;
    if (mag < 0x3C800000u) return 0;             // < 2^-6 -> 0
    if (mag > 0x43E00000u) mag = 0x43E00000u;    // clamp 448
    u32 r = mag + 0x7FFFFu + ((mag >> 20) & 1);  // RNE at bit 20
    u32 e = (r >> 20) - (120u << 3);
    if (e > 0x7E) e = 0x7E;
    return (u8)(((u >> 24) & 0x80) | e);
}
#endif

__device__ __forceinline__ void dec16(u32x4 v, float* f) {
    dec4(v.x, f);
    dec4(v.y, f + 4);
    dec4(v.z, f + 8);
    dec4(v.w, f + 12);
}

// ---------------------------------------------------------------------------
// K1: blocks 0..23 pack W0/W1/W2(padded) into MFMA B-fragment order (bf16 --
//     weights/MFMA stay bf16; only gathered ACTIVATIONS are fp8);
//     block 24 inits the 196 global bucket cursors to b*CAPB.
// ---------------------------------------------------------------------------
__global__ __launch_bounds__(256) void prep_init(
    const float* __restrict__ W0, const float* __restrict__ W1,
    const float* __restrict__ W2, u16* __restrict__ Wf,
    int* __restrict__ gCur)
{
    const int g = blockIdx.x, t = threadIdx.x;
    if (g == 24) {
        if (t < BKT) gCur[t] = t * CAPB;
        return;
    }
    int u = g * 4 + (t >> 6);               // 0..95
    int set = u >> 5, nt2 = (u >> 2) & 7, kt = u & 3;
    int lane = t & 63;
    const float* W = (set == 0) ? W0 : (set == 1) ? W1 : W2;
    int ld = (set == 2) ? 40 : 128;
    int ncols = (set == 2) ? 40 : 128;
    int n = nt2 * 16 + (lane & 15);
    int kb = kt * 32 + (lane >> 4) * 8;
    u16* dw = Wf + set * 16384 + (size_t)((nt2 * 4 + kt) * 64 + lane) * 8;
#pragma unroll
    for (int j = 0; j < 8; j++) {
        float v = (n < ncols) ? W[(kb + j) * ld + n] : 0.f;
        dw[j] = f2b(v);
    }
}

// ---------------------------------------------------------------------------
// K2: blocks [0,GB): 2-pass scatter with atomic batch reservation.
//     blocks [GB,..): layer-0 GEMM  t = bf16(x) @ W0, OUTPUT STORED FP8.
// fp8 rows (128B) enable the 8-lane/row gather map in K4/K5 (request halving).
// ---------------------------------------------------------------------------
__global__ __launch_bounds__(256) void scatter_gemm0(
    const int* __restrict__ src, const int* __restrict__ dst,
    int* __restrict__ gCur, u32* __restrict__ pairs,
    const float* __restrict__ A, const u16* __restrict__ Wf,
    u8* __restrict__ out, int N, int E)
{
    __shared__ int cnt[BKT];
    __shared__ int cur[BKT];
    const int t = threadIdx.x;
    if (blockIdx.x < GB) {
        const int g = blockIdx.x;
        for (int b = t; b < BKT; b += 256) cnt[b] = 0;
        __syncthreads();
        const int beg = g * EPB, end = min(E, beg + EPB);
        for (int e = beg + t; e < end; e += 256)
            atomicAdd(&cnt[dst[e] >> 8], 1);
        __syncthreads();
        for (int b = t; b < BKT; b += 256)
            cur[b] = atomicAdd(&gCur[b], cnt[b]);
        __syncthreads();
        for (int e = beg + t; e < end; e += 256) {
            int d = dst[e];
            int pos = atomicAdd(&cur[d >> 8], 1);
            pairs[pos] = ((u32)src[e] << 8) | (u32)(d & 255);
        }
        return;
    }
    // ---- gemm0 ----
    const int bx = blockIdx.x - GB;
    const int wave = t >> 6;
    const int lane = t & 63;
    const int m = lane & 15;
    const int q = lane >> 4;
    const int rowBase = bx * 64 + wave * 16;
    const int arow = rowBase + m;
    const bool rowOk = (arow < N);

    short8 af[4];
#pragma unroll
    for (int kt = 0; kt < 4; kt++) {
        if (rowOk) {
            float4 lo = *(const float4*)(A + (size_t)arow * 128 + kt * 32 + q * 8);
            float4 hi = *(const float4*)(A + (size_t)arow * 128 + kt * 32 + q * 8 + 4);
            short8 v;
            v[0] = (short)f2b(lo.x); v[1] = (short)f2b(lo.y);
            v[2] = (short)f2b(lo.z); v[3] = (short)f2b(lo.w);
            v[4] = (short)f2b(hi.x); v[5] = (short)f2b(hi.y);
            v[6] = (short)f2b(hi.z); v[7] = (short)f2b(hi.w);
            af[kt] = v;
        } else {
            af[kt] = (short8)0;
        }
    }

    f32x4 acc[8];
#pragma unroll
    for (int nt = 0; nt < 8; nt++) acc[nt] = (f32x4)0.f;

#pragma unroll
    for (int kt = 0; kt < 4; kt++) {
#pragma unroll
        for (int nt = 0; nt < 8; nt++) {
            short8 bf = *(const short8*)(Wf + (size_t)((nt * 4 + kt) * 64 + lane) * 8);
            acc[nt] = __builtin_amdgcn_mfma_f32_16x16x32_bf16(af[kt], bf, acc[nt], 0, 0, 0);
        }
    }

#pragma unroll
    for (int nt = 0; nt < 8; nt++) {
#pragma unroll
        for (int r = 0; r < 4; r++) {
            int orow = rowBase + q * 4 + r;
            if (orow < N) out[(size_t)orow * 128 + nt * 16 + m] = enc1(acc[nt][r]);
        }
    }
}

// ---------------------------------------------------------------------------
// K3: per-bucket node sort (round-0 256-key version; 2048-key variant was a
// measured regression, R1).
// ---------------------------------------------------------------------------
__global__ __launch_bounds__(256) void bucket_sort(
    const u32* __restrict__ pairs, const int* __restrict__ gCur,
    int* __restrict__ off, int* __restrict__ csr, int N, int E)
{
    __shared__ int sdeg[256];
    __shared__ int sex[256];
    __shared__ int scur[256];
    __shared__ int stage[CAP];
    const int b = blockIdx.x, t = threadIdx.x;

    int c0 = (t < BKT) ? (gCur[t] - t * CAPB) : 0;
    sex[t] = c0;
    __syncthreads();
    for (int d = 1; d < 256; d <<= 1) {
        int u = (t >= d) ? sex[t - d] : 0;
        __syncthreads();
        sex[t] += u;
        __syncthreads();
    }
    __shared__ int sBase, sCnt;
    if (t == b) { sBase = sex[t] - c0; sCnt = c0; }
    __syncthreads();
    const int base = sBase;
    const int cnt = sCnt;
    const int pbase = b * CAPB;
    __syncthreads();

    sdeg[t] = 0;
    __syncthreads();
    for (int i = t; i < cnt; i += 256)
        atomicAdd(&sdeg[pairs[pbase + i] & 255], 1);
    __syncthreads();

    int v = sdeg[t];
    sex[t] = v;
    __syncthreads();
    for (int d = 1; d < 256; d <<= 1) {
        int u = (t >= d) ? sex[t - d] : 0;
        __syncthreads();
        sex[t] += u;
        __syncthreads();
    }
    const int excl = sex[t] - v;
    const int node = b * 256 + t;
    if (node < N) off[node] = base + excl;
    if (b == BKT - 1 && t == 0) off[N] = E;
    scur[t] = excl;
    __syncthreads();

    if (cnt <= CAP) {
        for (int i = t; i < cnt; i += 256) {
            u32 p = pairs[pbase + i];
            int pos = atomicAdd(&scur[p & 255], 1);
            stage[pos] = (int)(p >> 8);
        }
        __syncthreads();
        for (int i = t; i < cnt; i += 256) csr[base + i] = stage[i];
    } else {
        for (int i = t; i < cnt; i += 256) {
            u32 p = pairs[pbase + i];
            int pos = atomicAdd(&scur[p & 255], 1);
            csr[base + pos] = (int)(p >> 8);
        }
    }
}

// ---------------------------------------------------------------------------
// K4/K5: FUSED layer: out = ( relu(agg(val_fp8) + bias) ) @ W
// block = 64 dst nodes, 512 threads (8 waves).
// phase 0 (R8, addressing FIXED R12): stage the block's CONTIGUOUS csr slice
//   into LDS, coalesced. The R11 crash was `sIdx - blkBeg` -- an intermediate
//   pointer 3.2MB before a 6KB LDS array; clang's InferAddressSpaces can wrap
//   it in 32-bit addrspace(3) -> flat fault. FIX: rebase the INTEGER index
//   (i - ib), keep both pointers in-range. Removes the csr global-load hop
//   (~200-600cy) from the gather's dependent chain; LDS read ~120cy instead.
//   Uniform fallback to global csr if slice > ECAP (Poisson(1024): ~never).
// phase 1: 8-lane/row gather (R7): 128B fp8 row = 8 lanes x 16B; halves
//   VMEM instructions/edge vs 16-lane and cuts serial depth ~1.8x (R7: -11us).
// phase 2: bf16 MFMA from LDS (weights bf16 -- unchanged numerics).
// OCOLS clamps stores to the true output width (stride-40 clobber bug, R11).
// OFP8: K4 stores tB as fp8 (gathered by K5); K5 stores t2 bf16 (K6 input).
// NOTE: val and out MUST differ (cross-block gather; in-place is a race).
// ---------------------------------------------------------------------------
template<int NT, int OSTRIDE, int OCOLS, bool OFP8>
__global__ __launch_bounds__(512) void agg_gemm_t(
    const u8* __restrict__ val, const int* __restrict__ off,
    const int* __restrict__ csr, const float* __restrict__ bias,
    const u16* __restrict__ Wf, void* __restrict__ outp, int N)
{
    __shared__ u16 A[64][136];   // 17.4 KB
    __shared__ int sIdx[ECAP];   // 6 KB
    const int tid = threadIdx.x;
    const int rowBase = blockIdx.x * 64;

    // ---- phase 0: stage block csr slice into LDS (coalesced)
    const int rowEndN = min(rowBase + 64, N);
    const int blkBeg = off[rowBase];
    const int blkEnd = off[rowEndN];
    const int blkCnt = blkEnd - blkBeg;
    const bool useLds = (blkCnt <= ECAP);
    if (useLds) {
        for (int i = tid; i < blkCnt; i += 512) sIdx[i] = csr[blkBeg + i];
    }
    __syncthreads();
    // index rebase (NOT pointer rebase -- R11 crash): LDS path uses local
    // indices [0, blkCnt); global path uses global edge indices.
    const int ib = useLds ? blkBeg : 0;
    const int* ip = useLds ? (const int*)sIdx : csr;

    // ---- phase 1: aggregate fp8 (8 lanes/row, 16B/lane), bias+relu -> LDS
    {
        const int c8 = tid & 7;          // 16B chunk (16 fp8 cols)
        const int nl = tid >> 3;         // 0..63 (all rows, one pass)
        const u8* vb = val + c8 * 16;
        const int node = rowBase + nl;
        const bool ok = (node < N);
        const int beg = (ok ? off[node] : 0) - ib;
        const int end = (ok ? off[node + 1] : 0) - ib;

        float a0[16], a1[16];
#pragma unroll
        for (int j = 0; j < 16; j++) { a0[j] = 0.f; a1[j] = 0.f; }

        int i = beg;
        for (; i + 3 < end; i += 4) {
            int s0 = ip[i], s1 = ip[i + 1], s2 = ip[i + 2], s3 = ip[i + 3];
            u32x4 v0 = *(const u32x4*)(vb + (size_t)s0 * 128);
            u32x4 v1 = *(const u32x4*)(vb + (size_t)s1 * 128);
            u32x4 v2 = *(const u32x4*)(vb + (size_t)s2 * 128);
            u32x4 v3 = *(const u32x4*)(vb + (size_t)s3 * 128);
            float f0[16], f1[16], f2[16], f3[16];
            dec16(v0, f0); dec16(v1, f1); dec16(v2, f2); dec16(v3, f3);
#pragma unroll
            for (int j = 0; j < 16; j++) {
                a0[j] += f0[j] + f2[j];
                a1[j] += f1[j] + f3[j];
            }
        }
        for (; i < end; i++) {
            int s0 = ip[i];
            u32x4 v0 = *(const u32x4*)(vb + (size_t)s0 * 128);
            float f0[16];
            dec16(v0, f0);
#pragma unroll
            for (int j = 0; j < 16; j++) a0[j] += f0[j];
        }

        float4 bA = *(const float4*)(bias + c8 * 16);
        float4 bB = *(const float4*)(bias + c8 * 16 + 4);
        float4 bC = *(const float4*)(bias + c8 * 16 + 8);
        float4 bD = *(const float4*)(bias + c8 * 16 + 12);
        float bb[16] = {bA.x, bA.y, bA.z, bA.w, bB.x, bB.y, bB.z, bB.w,
                        bC.x, bC.y, bC.z, bC.w, bD.x, bD.y, bD.z, bD.w};
        short8 o0, o1;
#pragma unroll
        for (int j = 0; j < 8; j++)
            o0[j] = (short)f2b(fmaxf(a0[j] + a1[j] + bb[j], 0.f));
#pragma unroll
        for (int j = 0; j < 8; j++)
            o1[j] = (short)f2b(fmaxf(a0[j + 8] + a1[j + 8] + bb[j + 8], 0.f));
        *(short8*)&A[nl][c8 * 16] = o0;
        *(short8*)&A[nl][c8 * 16 + 8] = o1;
    }
    __syncthreads();

    // ---- phase 2: MFMA from LDS
    const int wave = tid >> 6;           // 0..7
    const int lane = tid & 63;
    const int m = lane & 15;
    const int q = lane >> 4;
    const int rg = wave & 3;             // row group (16 rows)
    const int ch = wave >> 2;            // col half
    const int lrow = rg * 16 + m;

    short8 af[4];
#pragma unroll
    for (int kt = 0; kt < 4; kt++)
        af[kt] = *(const short8*)&A[lrow][kt * 32 + q * 8];

    constexpr int NTH = (NT + 1) / 2;
    const int ntB = ch ? NTH : 0;
    const int ntE = ch ? NT : NTH;

    f32x4 acc[NTH];
#pragma unroll
    for (int i = 0; i < NTH; i++) acc[i] = (f32x4)0.f;

#pragma unroll
    for (int kt = 0; kt < 4; kt++) {
        for (int nt = ntB; nt < ntE; nt++) {
            short8 bf = *(const short8*)(Wf + (size_t)((nt * 4 + kt) * 64 + lane) * 8);
            acc[nt - ntB] = __builtin_amdgcn_mfma_f32_16x16x32_bf16(af[kt], bf, acc[nt - ntB], 0, 0, 0);
        }
    }

    for (int nt = ntB; nt < ntE; nt++) {
        const int col = nt * 16 + m;
        if (col < OCOLS) {
#pragma unroll
            for (int r = 0; r < 4; r++) {
                int orow = rowBase + rg * 16 + q * 4 + r;
                if (orow < N) {
                    if constexpr (OFP8) {
                        ((u8*)outp)[(size_t)orow * OSTRIDE + col] = enc1(acc[nt - ntB][r]);
                    } else {
                        ((u16*)outp)[(size_t)orow * OSTRIDE + col] = f2b(acc[nt - ntB][r]);
                    }
                }
            }
        }
    }
}

// ---------------------------------------------------------------------------
// K6: aggregate first 40 feats of bf16 stride-40 rows, + b2 -> fp32 d_out.
// R8 staging with R12 index-rebase fix (no out-of-range pointers).
// (t2 kept bf16: limits fp8 quantization boundaries to t and tB)
// ---------------------------------------------------------------------------
__global__ __launch_bounds__(256) void agg40b(
    const u16* __restrict__ val, const int* __restrict__ off,
    const int* __restrict__ csr, const float* __restrict__ b2,
    float* __restrict__ out, int N)
{
    __shared__ int sIdx[ECAP6];
    const int t = threadIdx.x;
    const int nodeBase = blockIdx.x * 16;
    const int nodeEndN = min(nodeBase + 16, N);
    const int blkBeg = off[nodeBase];
    const int blkEnd = off[nodeEndN];
    const int blkCnt = blkEnd - blkBeg;
    const bool useLds = (blkCnt <= ECAP6);
    if (useLds) {
        for (int i = t; i < blkCnt; i += 256) sIdx[i] = csr[blkBeg + i];
    }
    __syncthreads();
    const int ib = useLds ? blkBeg : 0;
    const int* ip = useLds ? (const int*)sIdx : csr;

    const int c = t & 15;
    const int node = nodeBase + (t >> 4);
    if (node >= N || c >= 10) return;
    const int beg = off[node] - ib, end = off[node + 1] - ib;

    float a0[4] = {0, 0, 0, 0};
    float a1[4] = {0, 0, 0, 0};
    int i = beg;
    for (; i + 1 < end; i += 2) {
        int s0 = ip[i];
        int s1 = ip[i + 1];
        ushort4v v0 = *(const ushort4v*)(val + (size_t)s0 * 40 + c * 4);
        ushort4v v1 = *(const ushort4v*)(val + (size_t)s1 * 40 + c * 4);
        a0[0] += b2f(v0.x); a0[1] += b2f(v0.y); a0[2] += b2f(v0.z); a0[3] += b2f(v0.w);
        a1[0] += b2f(v1.x); a1[1] += b2f(v1.y); a1[2] += b2f(v1.z); a1[3] += b2f(v1.w);
    }
    if (i < end) {
        int s0 = ip[i];
        ushort4v v0 = *(const ushort4v*)(val + (size_t)s0 * 40 + c * 4);
        a0[0] += b2f(v0.x); a0[1] += b2f(v0.y); a0[2] += b2f(v0.z); a0[3] += b2f(v0.w);
    }
    float4 b = *(const float4*)(b2 + c * 4);
    float4 r;
    r.x = a0[0] + a1[0] + b.x;
    r.y = a0[1] + a1[1] + b.y;
    r.z = a0[2] + a1[2] + b.z;
    r.w = a0[3] + a1[3] + b.w;
    *(float4*)(out + (size_t)node * 40 + c * 4) = r;
}

extern "C" void kernel_launch(void* const* d_in, const int* in_sizes, int n_in,
                              void* d_out, int out_size, void* d_ws, size_t ws_size,
                              hipStream_t stream)
{
    const float* x  = (const float*)d_in[0];
    const int*   ei = (const int*)d_in[1];
    const float* W0 = (const float*)d_in[2];
    const float* b0 = (const float*)d_in[3];
    const float* W1 = (const float*)d_in[4];
    const float* b1 = (const float*)d_in[5];
    const float* W2 = (const float*)d_in[6];
    const float* b2 = (const float*)d_in[7];
    float* out = (float*)d_out;

    const int N = NN, E = EE;
    const int* src = ei;        // edge_index[0]
    const int* dst = ei + E;    // edge_index[1]

    char* ws = (char*)d_ws;
    u8*  t     = (u8*)ws;                           // 6.4 MB (layer-0 out, fp8)
    u8*  tB    = (u8*)(ws + 6400000);               // 6.4 MB (layer-1 out, fp8)
    u16* t2    = (u16*)(ws + 12800000);             // 4.0 MB (layer-2, bf16 stride 40)
    u16* Wf    = (u16*)(ws + 16800000);             // 96 KB (frag-packed W, bf16)
    int* off   = (int*)(ws + 16900000);             // 200 KB (N+1)
    int* csr   = (int*)(ws + 17100008);             // 3.2 MB
    int* gCur  = (int*)(ws + 20300008);             // 784 B (bucket cursors)
    u32* pairs = (u32*)(ws + 20300800);             // 4.82 MB (196*6144*4)

    const int tileGrid = (N + 63) / 64;             // 782
    const int agg40Grid = (N + 15) / 16;            // 3125

    // K1: weight packing + bucket-cursor init
    prep_init<<<25, 256, 0, stream>>>(W0, W1, W2, Wf, gCur);
    // K2: batch-reserved scatter + layer-0 GEMM (fp8 out)
    scatter_gemm0<<<GB + tileGrid, 256, 0, stream>>>(src, dst, gCur, pairs,
                                                     x, Wf, t, N, E);
    // K3: per-bucket sort -> off[] + csr[]
    bucket_sort<<<BKT, 256, 0, stream>>>(pairs, gCur, off, csr, N, E);

    // K4: layer 1 fused: tB(fp8) = relu(agg(t_fp8) + b0) @ W1
    agg_gemm_t<8, 128, 128, true><<<tileGrid, 512, 0, stream>>>(
        t, off, csr, b0, Wf + 16384, (void*)tB, N);
    // K5: layer 2 fused: t2(bf16) = relu(agg(tB_fp8) + b1) @ W2pad, 40 cols
    agg_gemm_t<3, 40, 40, false><<<tileGrid, 512, 0, stream>>>(
        tB, off, csr, b1, Wf + 32768, (void*)t2, N);
    // K6: out = agg40(t2) + b2
    agg40b<<<agg40Grid, 256, 0, stream>>>(t2, off, csr, b2, out, N);
}